// Round 6
// baseline (342.745 us; speedup 1.0000x reference)
//
#include <hip/hip_runtime.h>

#define NB 8
#define NT 2048
#define NC 2048
#define NH 128

typedef short s8v __attribute__((ext_vector_type(8)));   // 8 bf16 (4 VGPRs) — MFMA A/B frag
typedef float f4  __attribute__((ext_vector_type(4)));   // 4 fp32 — MFMA C/D frag

static __device__ __forceinline__ unsigned short f2bf(float f) {
    union { float f; unsigned int u; } v; v.f = f;
    unsigned int x = v.u;
    return (unsigned short)((x + 0x7FFFu + ((x >> 16) & 1u)) >> 16);  // RNE
}

// async global->LDS, 16B/lane; LDS dest = wave-uniform base + lane*16 (HW adds lane term)
static __device__ __forceinline__ void gl2lds16(const void* g, void* lds_base) {
    __builtin_amdgcn_global_load_lds(
        (const __attribute__((address_space(1))) unsigned int*)g,
        (__attribute__((address_space(3))) unsigned int*)lds_base, 16, 0, 0);
}

// ---------------------------------------------------------------------------
// Kernel 0: transpose + cast W[k][n] (2048x128 fp32) -> Wt[n][k] (128x2048 bf16)
// via LDS tile. grid (32 k-tiles of 64, 3 mats), block 256.
// ---------------------------------------------------------------------------
__global__ __launch_bounds__(256) void wtrans_k(
    const float* __restrict__ Wk, const float* __restrict__ Wq,
    const float* __restrict__ Wv, unsigned short* __restrict__ wt)
{
    __shared__ float Ls[64][129];                       // +1 pad: conflict-free transpose
    const int mat = blockIdx.y;
    const float* W = (mat == 0) ? Wq : (mat == 1) ? Wk : Wv;
    const int k0 = blockIdx.x * 64;
    const int t  = threadIdx.x;

    #pragma unroll
    for (int j = 0; j < 8; ++j) {
        int flat = j * 1024 + t * 4;
        int k = flat >> 7, n = flat & 127;
        f4 v = *reinterpret_cast<const f4*>(W + (size_t)(k0 + k) * NH + n);
        Ls[k][n] = v[0]; Ls[k][n + 1] = v[1]; Ls[k][n + 2] = v[2]; Ls[k][n + 3] = v[3];
    }
    __syncthreads();

    const int n = t >> 1, half = t & 1;
    unsigned short tmp[32];
    #pragma unroll
    for (int kk = 0; kk < 32; ++kk) tmp[kk] = f2bf(Ls[half * 32 + kk][n]);
    unsigned short* dst = wt + (size_t)mat * 262144 + (size_t)n * 2048 + k0 + half * 32;
    #pragma unroll
    for (int v = 0; v < 4; ++v)
        *reinterpret_cast<s8v*>(dst + v * 8) = *reinterpret_cast<s8v*>(tmp + v * 8);
}

// ---------------------------------------------------------------------------
// Kernel 1: fused projection + RoPE, v4 (v3 + register-prefetch pipeline).
// grid = (256 row-tiles of 64, 3 mats), block 256 (4 waves, 2m x 2n).
// Tile M=64 N=128 BK=128. A: fp32 global -> REGISTER PREFETCH (1 iter ahead)
// -> v_perm trunc-pack -> ds_write_b64. B: async global_load_lds.
// Both LDS tiles XOR-swizzled (256B rows, 16 chunks, pos = c ^ (row&15)).
// Per wave per K-step: 32 MFMA, 24 conflict-free ds_read_b128.
// ---------------------------------------------------------------------------
__global__ __launch_bounds__(256) void proj_rope(
    const float* __restrict__ x, const unsigned short* __restrict__ wt,
    unsigned short* __restrict__ qws, unsigned short* __restrict__ kws,
    unsigned short* __restrict__ vtws)
{
    __shared__ char LDS[49152];
    char* AsB = LDS;                // 64 rows x 256 B  = 16 KB (bf16, swizzled)
    char* BsB = LDS + 16384;        // 128 rows x 256 B = 32 KB (bf16, swizzled)

    const int mat  = blockIdx.y;
    const int tid  = threadIdx.x;
    const int wave = tid >> 6;
    const int lane = tid & 63;
    const int quad = lane >> 4, l16 = lane & 15;
    const int wm = wave >> 1, wn = wave & 1;
    const int M0 = blockIdx.x * 64;
    const unsigned short* wtm = wt + mat * (NH * NC);

    // ---- A-staging: thread handles 8 f4s; f = tid + s*256 -> row f>>5, kc (f&31)*4
    const float* asrc[8];
    unsigned int adst[8];
    #pragma unroll
    for (int s = 0; s < 8; ++s) {
        const int f   = tid + s * 256;
        const int row = f >> 5;
        const int kc  = (f & 31) * 4;
        asrc[s] = x + (size_t)(M0 + row) * NC + kc;
        const int c   = kc >> 3;
        const int pos = c ^ (row & 15);
        adst[s] = row * 256 + pos * 16 + (kc & 4) * 2;
    }

    // ---- B-staging: 8 gl2lds per wave
    const unsigned short* bsrc[8];
    #pragma unroll
    for (int s = 0; s < 8; ++s) {
        const int j   = wave * 8 + s;
        const int row = j * 4 + (lane >> 4);
        const int c   = (lane & 15) ^ (row & 15);
        bsrc[s] = wtm + (size_t)row * NC + c * 8;
    }

    f4 acc[2][4];
    #pragma unroll
    for (int mi = 0; mi < 2; ++mi)
        #pragma unroll
        for (int ni = 0; ni < 4; ++ni)
            acc[mi][ni] = (f4){0.f, 0.f, 0.f, 0.f};

    // preload A registers for iteration 0
    f4 areg[8];
    #pragma unroll
    for (int s = 0; s < 8; ++s)
        areg[s] = *reinterpret_cast<const f4*>(asrc[s]);

    for (int kk = 0; kk < NC; kk += 128) {
        // B tile via async DMA
        #pragma unroll
        for (int s = 0; s < 8; ++s)
            gl2lds16(bsrc[s] + kk, BsB + (wave * 8 + s) * 1024);

        // A tile: pack prefetched regs -> LDS
        #pragma unroll
        for (int s = 0; s < 8; ++s) {
            union { f4 f; unsigned int u[4]; } v; v.f = areg[s];
            uint2 p;
            p.x = __builtin_amdgcn_perm(v.u[1], v.u[0], 0x07060302u);
            p.y = __builtin_amdgcn_perm(v.u[3], v.u[2], 0x07060302u);
            *reinterpret_cast<uint2*>(AsB + adst[s]) = p;
        }
        // prefetch next iteration's A into regs (latency hides under MFMAs+barriers)
        if (kk + 128 < NC) {
            #pragma unroll
            for (int s = 0; s < 8; ++s)
                areg[s] = *reinterpret_cast<const f4*>(asrc[s] + kk + 128);
        }
        __syncthreads();

        #pragma unroll
        for (int ksub = 0; ksub < 4; ++ksub) {
            const int c = ksub * 4 + quad;
            s8v a[2];
            #pragma unroll
            for (int mi = 0; mi < 2; ++mi) {
                const int row = wm * 32 + mi * 16 + l16;   // row&15 == l16
                a[mi] = *reinterpret_cast<const s8v*>(AsB + row * 256 + (c ^ l16) * 16);
            }
            #pragma unroll
            for (int ni = 0; ni < 4; ++ni) {
                const int row2 = wn * 64 + ni * 16 + l16;
                s8v b = *reinterpret_cast<const s8v*>(BsB + row2 * 256 + (c ^ l16) * 16);
                acc[0][ni] = __builtin_amdgcn_mfma_f32_16x16x32_bf16(a[0], b, acc[0][ni], 0, 0, 0);
                acc[1][ni] = __builtin_amdgcn_mfma_f32_16x16x32_bf16(a[1], b, acc[1][ni], 0, 0, 0);
            }
        }
        __syncthreads();
    }

    // epilogue: C/D layout col = l16-part, row = quad*4 + r
    const float cfreq = -0.10381025296f;  // -log2(10000)/128
    #pragma unroll
    for (int mi = 0; mi < 2; ++mi) {
        #pragma unroll
        for (int ni = 0; ni < 4; ++ni) {
            const int col = wn * 64 + ni * 16 + l16;
            #pragma unroll
            for (int r = 0; r < 4; ++r) {
                const int row = M0 + wm * 32 + mi * 16 + quad * 4 + r;  // b*T + t
                const int t   = row & (NT - 1);
                float v = acc[mi][ni][r];
                if (mat < 2) {
                    float other = __shfl_xor(v, 1, 64);
                    float freq  = exp2f(cfreq * (float)(col & ~1));
                    float ang   = (float)t * freq;
                    float sn = sinf(ang), cs = cosf(ang);
                    v = (col & 1) ? (other * sn + v * cs)
                                  : (v * cs - other * sn);
                }
                unsigned short bv = f2bf(v);
                if (mat == 0)      qws[(size_t)row * NH + col] = bv;
                else if (mat == 1) kws[(size_t)row * NH + col] = bv;
                else {
                    int b = row >> 11;
                    vtws[(size_t)b * (NH * NT) + (size_t)col * NT + t] = bv;
                }
            }
        }
    }
}

// ---------------------------------------------------------------------------
// Kernel 2: flash attention (causal). 16 q-rows per wave, split-KV stride 4
// across the block's 4 waves, private online-softmax state, LDS merge at end.
// grid = (128 q-tiles of 16, 8 batches), block 256, 24.3 KB LDS -> 3-4 blk/CU.
// P buffer XOR-swizzled (8-short chunks) -> conflict-free b128 A-frag reads.
// ---------------------------------------------------------------------------
__global__ __launch_bounds__(256, 3) void attn_k(
    const unsigned short* __restrict__ qws, const unsigned short* __restrict__ kws,
    const unsigned short* __restrict__ vtws, float* __restrict__ out)
{
    __shared__ unsigned short P[4][16 * 64];   // 8 KB, per-wave, swizzled
    __shared__ float Os[4][16][64];            // 16 KB (one half of d per pass)
    __shared__ float Ms[4][16], Ls[4][16], Lt[16];

    const int wave = threadIdx.x >> 6;
    const int lane = threadIdx.x & 63;
    const int quad = lane >> 4, l16 = lane & 15;
    const int b     = blockIdx.y;
    const int qrow0 = blockIdx.x * 16;
    const unsigned short* Q  = qws  + (size_t)b * NT * NH;
    const unsigned short* K  = kws  + (size_t)b * NT * NH;
    const unsigned short* Vt = vtws + (size_t)b * NH * NT;

    s8v qf[4];
    #pragma unroll
    for (int ks = 0; ks < 4; ++ks)
        qf[ks] = *reinterpret_cast<const s8v*>(
            Q + (size_t)(qrow0 + l16) * NH + ks * 32 + quad * 8);

    float m[4], ls[4];
    f4 o[8];
    #pragma unroll
    for (int r = 0; r < 4; ++r) { m[r] = -INFINITY; ls[r] = 0.f; }
    #pragma unroll
    for (int dt = 0; dt < 8; ++dt) o[dt] = (f4){0.f, 0.f, 0.f, 0.f};

    const int nkt = (qrow0 >> 6) + 1;        // 64-wide kv tiles, causal
    const float scale = 0.0883883476f;       // 1/sqrt(128)

    for (int kt = wave; kt < nkt; kt += 4) {
        const int kbase = kt * 64;
        const bool domask = (kt == nkt - 1);

        // S = Q K^T
        f4 s[4];
        #pragma unroll
        for (int nt = 0; nt < 4; ++nt) {
            f4 a = (f4){0.f, 0.f, 0.f, 0.f};
            #pragma unroll
            for (int ks = 0; ks < 4; ++ks) {
                s8v kf = *reinterpret_cast<const s8v*>(
                    K + (size_t)(kbase + nt * 16 + l16) * NH + ks * 32 + quad * 8);
                a = __builtin_amdgcn_mfma_f32_16x16x32_bf16(qf[ks], kf, a, 0, 0, 0);
            }
            s[nt] = a;
        }

        // online softmax; per-lane lsum (reduced after loop)
        #pragma unroll
        for (int r = 0; r < 4; ++r) {
            const int trow = qrow0 + quad * 4 + r;
            #pragma unroll
            for (int nt = 0; nt < 4; ++nt) {
                float sv = s[nt][r] * scale;
                if (domask && (kbase + nt * 16 + l16 > trow)) sv = -INFINITY;
                s[nt][r] = sv;
            }
            float tm = fmaxf(fmaxf(s[0][r], s[1][r]), fmaxf(s[2][r], s[3][r]));
            #pragma unroll
            for (int off = 1; off < 16; off <<= 1)
                tm = fmaxf(tm, __shfl_xor(tm, off, 64));
            const float mn = fmaxf(m[r], tm);
            const float alpha = __expf(m[r] - mn);
            m[r] = mn;
            float rs = 0.f;
            #pragma unroll
            for (int nt = 0; nt < 4; ++nt) {
                float p = __expf(s[nt][r] - mn);
                s[nt][r] = p;
                rs += p;
            }
            ls[r] = ls[r] * alpha + rs;
            #pragma unroll
            for (int dt = 0; dt < 8; ++dt) o[dt][r] *= alpha;
        }

        // P (C layout) -> LDS, XOR-swizzled: pos = chunk ^ (row&7), chunk = 8 shorts
        #pragma unroll
        for (int nt = 0; nt < 4; ++nt)
            #pragma unroll
            for (int r = 0; r < 4; ++r) {
                const int prow = quad * 4 + r;
                const int swz  = ((nt * 2 + (l16 >> 3)) ^ (prow & 7)) * 8 + (l16 & 7);
                P[wave][prow * 64 + swz] = f2bf(s[nt][r]);
            }

        // O += P @ V
        #pragma unroll
        for (int ks2 = 0; ks2 < 2; ++ks2) {
            const int pp = (ks2 * 4 + quad) ^ (l16 & 7);
            s8v pa = *reinterpret_cast<const s8v*>(&P[wave][l16 * 64 + pp * 8]);
            #pragma unroll
            for (int dt = 0; dt < 8; ++dt) {
                s8v vf = *reinterpret_cast<const s8v*>(
                    Vt + (size_t)(dt * 16 + l16) * NT + kbase + ks2 * 32 + quad * 8);
                o[dt] = __builtin_amdgcn_mfma_f32_16x16x32_bf16(pa, vf, o[dt], 0, 0, 0);
            }
        }
    }

    // reduce per-lane lsum across the 16-lane row group
    #pragma unroll
    for (int r = 0; r < 4; ++r) {
        float v = ls[r];
        #pragma unroll
        for (int off = 1; off < 16; off <<= 1) v += __shfl_xor(v, off, 64);
        ls[r] = v;
    }

    // ---- merge the 4 per-wave partials ----
    if (l16 == 0) {
        #pragma unroll
        for (int r = 0; r < 4; ++r) {
            Ms[wave][quad * 4 + r] = m[r];
            Ls[wave][quad * 4 + r] = ls[r];
        }
    }
    __syncthreads();

    #pragma unroll
    for (int r = 0; r < 4; ++r) {
        const int row = quad * 4 + r;
        float M = fmaxf(fmaxf(Ms[0][row], Ms[1][row]), fmaxf(Ms[2][row], Ms[3][row]));
        float sc = __expf(m[r] - M);
        float lt = Ls[0][row] * __expf(Ms[0][row] - M) + Ls[1][row] * __expf(Ms[1][row] - M)
                 + Ls[2][row] * __expf(Ms[2][row] - M) + Ls[3][row] * __expf(Ms[3][row] - M);
        if (wave == 0 && l16 == 0) Lt[row] = lt;
        #pragma unroll
        for (int dt = 0; dt < 8; ++dt) o[dt][r] *= sc;
    }

    const int rrow = threadIdx.x >> 4;          // 0..15
    const int cx   = (threadIdx.x & 15) * 4;    // 0..60
    #pragma unroll
    for (int h = 0; h < 2; ++h) {
        __syncthreads();
        #pragma unroll
        for (int dtl = 0; dtl < 4; ++dtl)
            #pragma unroll
            for (int r = 0; r < 4; ++r)
                Os[wave][quad * 4 + r][dtl * 16 + l16] = o[h * 4 + dtl][r];
        __syncthreads();
        f4 sum = (f4){0.f, 0.f, 0.f, 0.f};
        #pragma unroll
        for (int w = 0; w < 4; ++w)
            sum += *reinterpret_cast<const f4*>(&Os[w][rrow][cx]);
        const float rl = 1.0f / Lt[rrow];
        *reinterpret_cast<f4*>(
            &out[((size_t)b * NT + qrow0 + rrow) * NH + h * 64 + cx]) = sum * rl;
    }
}

// ---------------------------------------------------------------------------
extern "C" void kernel_launch(void* const* d_in, const int* in_sizes, int n_in,
                              void* d_out, int out_size, void* d_ws, size_t ws_size,
                              hipStream_t stream) {
    const float* x  = (const float*)d_in[0];
    const float* Wk = (const float*)d_in[1];
    const float* Wq = (const float*)d_in[2];
    const float* Wv = (const float*)d_in[3];
    unsigned short* ws   = (unsigned short*)d_ws;
    unsigned short* wt   = ws;                      // 3 * 262144 (Wt: Q,K,V) bf16
    unsigned short* qws  = ws  + 786432;            // 8*2048*128  RoPE'd Q (bf16)
    unsigned short* kws  = qws + 2097152;           // 8*2048*128  RoPE'd K (bf16)
    unsigned short* vtws = kws + 2097152;           // 8*128*2048  V transposed (bf16)
    float* outp = (float*)d_out;

    wtrans_k<<<dim3(32, 3), 256, 0, stream>>>(Wk, Wq, Wv, wt);
    proj_rope<<<dim3(256, 3), 256, 0, stream>>>(x, wt, qws, kws, vtws);
    attn_k<<<dim3(128, 8), 256, 0, stream>>>(qws, kws, vtws, outp);
}

// Round 7
// 326.749 us; speedup vs baseline: 1.0490x; 1.0490x over previous
//
#include <hip/hip_runtime.h>

#define NB 8
#define NT 2048
#define NC 2048
#define NH 128

typedef short s8v __attribute__((ext_vector_type(8)));   // 8 bf16 (4 VGPRs) — MFMA A/B frag
typedef float f4  __attribute__((ext_vector_type(4)));   // 4 fp32 — MFMA C/D frag

static __device__ __forceinline__ unsigned short f2bf(float f) {
    union { float f; unsigned int u; } v; v.f = f;
    unsigned int x = v.u;
    return (unsigned short)((x + 0x7FFFu + ((x >> 16) & 1u)) >> 16);  // RNE
}

// async global->LDS, 16B/lane; LDS dest = wave-uniform base + lane*16 (HW adds lane term)
static __device__ __forceinline__ void gl2lds16(const void* g, void* lds_base) {
    __builtin_amdgcn_global_load_lds(
        (const __attribute__((address_space(1))) unsigned int*)g,
        (__attribute__((address_space(3))) unsigned int*)lds_base, 16, 0, 0);
}

// ---------------------------------------------------------------------------
// Kernel 0: transpose + cast W[k][n] (2048x128 fp32) -> Wt[n][k] (128x2048 bf16)
// via LDS tile. grid (32 k-tiles of 64, 3 mats), block 256.
// ---------------------------------------------------------------------------
__global__ __launch_bounds__(256) void wtrans_k(
    const float* __restrict__ Wk, const float* __restrict__ Wq,
    const float* __restrict__ Wv, unsigned short* __restrict__ wt)
{
    __shared__ float Ls[64][129];                       // +1 pad: conflict-free transpose
    const int mat = blockIdx.y;
    const float* W = (mat == 0) ? Wq : (mat == 1) ? Wk : Wv;
    const int k0 = blockIdx.x * 64;
    const int t  = threadIdx.x;

    #pragma unroll
    for (int j = 0; j < 8; ++j) {
        int flat = j * 1024 + t * 4;
        int k = flat >> 7, n = flat & 127;
        f4 v = *reinterpret_cast<const f4*>(W + (size_t)(k0 + k) * NH + n);
        Ls[k][n] = v[0]; Ls[k][n + 1] = v[1]; Ls[k][n + 2] = v[2]; Ls[k][n + 3] = v[3];
    }
    __syncthreads();

    const int n = t >> 1, half = t & 1;
    unsigned short tmp[32];
    #pragma unroll
    for (int kk = 0; kk < 32; ++kk) tmp[kk] = f2bf(Ls[half * 32 + kk][n]);
    unsigned short* dst = wt + (size_t)mat * 262144 + (size_t)n * 2048 + k0 + half * 32;
    #pragma unroll
    for (int v = 0; v < 4; ++v)
        *reinterpret_cast<s8v*>(dst + v * 8) = *reinterpret_cast<s8v*>(tmp + v * 8);
}

// ---------------------------------------------------------------------------
// Kernel 1: fused projection + RoPE (R4 structure — best measured: 82.7 us).
// grid = (256 row-tiles of 64, 3 mats), block 256 (4 waves, 2m x 2n).
// Tile M=64 N=128 BK=64. BOTH operands staged via fire-and-forget
// global_load_lds with XOR chunk swizzle. Xs: 64x64 fp32 (16KB); Bs: 128x64
// bf16 (16KB). A packed fp32->bf16 by truncation (v_perm). 3 blocks/CU.
// ---------------------------------------------------------------------------
__global__ __launch_bounds__(256) void proj_rope(
    const float* __restrict__ x, const unsigned short* __restrict__ wt,
    unsigned short* __restrict__ qws, unsigned short* __restrict__ kws,
    unsigned short* __restrict__ vtws)
{
    __shared__ char LDS[32768];
    char* XsB = LDS;                // 16 KB
    char* BsB = LDS + 16384;        // 16 KB

    const int mat  = blockIdx.y;
    const int wave = threadIdx.x >> 6;
    const int lane = threadIdx.x & 63;
    const int quad = lane >> 4, l16 = lane & 15;
    const int wm = wave >> 1, wn = wave & 1;
    const int M0 = blockIdx.x * 64;
    const unsigned short* wtm = wt + mat * (NH * NC);

    // staging source addresses (swizzled chunk on the GLOBAL side; LDS dest contiguous)
    const float* xbase[4]; const unsigned short* bbase[4];
    const int bc = (lane & 7) ^ (lane >> 3);            // B chunk, row&7 == lane>>3
    #pragma unroll
    for (int s = 0; s < 4; ++s) {
        const int xrow = wave * 16 + s * 4 + (lane >> 4);
        const int xcol = ((lane & 15) ^ (xrow & 15)) * 4;
        xbase[s] = x + (size_t)(M0 + xrow) * NC + xcol;
        const int brow = wave * 32 + s * 8 + (lane >> 3);
        bbase[s] = wtm + (size_t)brow * NC + bc * 8;
    }

    f4 acc[2][4];
    #pragma unroll
    for (int mi = 0; mi < 2; ++mi)
        #pragma unroll
        for (int ni = 0; ni < 4; ++ni)
            acc[mi][ni] = (f4){0.f, 0.f, 0.f, 0.f};

    for (int kk = 0; kk < NC; kk += 64) {
        #pragma unroll
        for (int s = 0; s < 4; ++s)
            gl2lds16(xbase[s] + kk, XsB + (wave * 4 + s) * 1024);
        #pragma unroll
        for (int s = 0; s < 4; ++s)
            gl2lds16(bbase[s] + kk, BsB + (wave * 4 + s) * 1024);
        __syncthreads();

        #pragma unroll
        for (int ksub = 0; ksub < 2; ++ksub) {
            s8v a[2];
            #pragma unroll
            for (int mi = 0; mi < 2; ++mi) {
                const int rb = (wm * 32 + mi * 16 + l16) * 256;   // row*256B, row&15==l16
                const int p0 = (ksub * 8 + quad * 2) ^ l16;       // even chunk
                union { f4 f; unsigned int u[4]; } L, H;
                L.f = *reinterpret_cast<const f4*>(XsB + rb + p0 * 16);
                H.f = *reinterpret_cast<const f4*>(XsB + rb + (p0 ^ 1) * 16);
                union { s8v s; unsigned int u[4]; } A;
                A.u[0] = __builtin_amdgcn_perm(L.u[1], L.u[0], 0x07060302u);
                A.u[1] = __builtin_amdgcn_perm(L.u[3], L.u[2], 0x07060302u);
                A.u[2] = __builtin_amdgcn_perm(H.u[1], H.u[0], 0x07060302u);
                A.u[3] = __builtin_amdgcn_perm(H.u[3], H.u[2], 0x07060302u);
                a[mi] = A.s;
            }
            #pragma unroll
            for (int ni = 0; ni < 4; ++ni) {
                const int row2 = wn * 64 + ni * 16 + l16;         // row&7 == l16&7
                const int pb = (ksub * 4 + quad) ^ (l16 & 7);
                s8v b = *reinterpret_cast<const s8v*>(BsB + row2 * 128 + pb * 16);
                acc[0][ni] = __builtin_amdgcn_mfma_f32_16x16x32_bf16(a[0], b, acc[0][ni], 0, 0, 0);
                acc[1][ni] = __builtin_amdgcn_mfma_f32_16x16x32_bf16(a[1], b, acc[1][ni], 0, 0, 0);
            }
        }
        __syncthreads();
    }

    // epilogue: C/D layout col = l16-part, row = quad*4 + r
    const float cfreq = -0.10381025296f;  // -log2(10000)/128
    #pragma unroll
    for (int mi = 0; mi < 2; ++mi) {
        #pragma unroll
        for (int ni = 0; ni < 4; ++ni) {
            const int col = wn * 64 + ni * 16 + l16;
            #pragma unroll
            for (int r = 0; r < 4; ++r) {
                const int row = M0 + wm * 32 + mi * 16 + quad * 4 + r;  // b*T + t
                const int t   = row & (NT - 1);
                float v = acc[mi][ni][r];
                if (mat < 2) {
                    float other = __shfl_xor(v, 1, 64);
                    float freq  = exp2f(cfreq * (float)(col & ~1));
                    float ang   = (float)t * freq;
                    float sn = sinf(ang), cs = cosf(ang);
                    v = (col & 1) ? (other * sn + v * cs)
                                  : (v * cs - other * sn);
                }
                unsigned short bv = f2bf(v);
                if (mat == 0)      qws[(size_t)row * NH + col] = bv;
                else if (mat == 1) kws[(size_t)row * NH + col] = bv;
                else {
                    int b = row >> 11;
                    vtws[(size_t)b * (NH * NT) + (size_t)col * NT + t] = bv;
                }
            }
        }
    }
}

// ---------------------------------------------------------------------------
// Kernel 2: flash attention (causal), load-balanced pair scheduling.
// grid = (64 pairs, 8 batches), block = 512 (8 waves).
// Block bx handles q-tiles bx and 127-bx (16 rows each): combined causal work
// is EXACTLY 33 kv-tiles for every pair -> perfectly uniform blocks, 2/CU.
// Within a phase, wave w processes kv-tiles kt = w, w+8, ... with private
// online-softmax state; 8-way merge via LDS at phase end.
// P buffers XOR-swizzled -> conflict-free b128 A-frag reads.
// ---------------------------------------------------------------------------
__global__ __launch_bounds__(512, 4) void attn_k(
    const unsigned short* __restrict__ qws, const unsigned short* __restrict__ kws,
    const unsigned short* __restrict__ vtws, float* __restrict__ out)
{
    __shared__ unsigned short P[8][16 * 64];   // 16 KB, per-wave, swizzled
    __shared__ float Os[8][16][64];            // 32 KB (one half of d per pass)
    __shared__ float Ms[8][16], Ls[8][16], Lt[16];

    const int tid  = threadIdx.x;
    const int wave = tid >> 6;
    const int lane = tid & 63;
    const int quad = lane >> 4, l16 = lane & 15;
    const int b    = blockIdx.y;
    const unsigned short* Q  = qws  + (size_t)b * NT * NH;
    const unsigned short* K  = kws  + (size_t)b * NT * NH;
    const unsigned short* Vt = vtws + (size_t)b * NH * NT;
    const float scale = 0.0883883476f;       // 1/sqrt(128)

    #pragma unroll
    for (int phase = 0; phase < 2; ++phase) {
        const int qt    = phase == 0 ? (int)blockIdx.x : 127 - (int)blockIdx.x;
        const int qrow0 = qt * 16;
        const int nkt   = (qt >> 2) + 1;

        // Q fragments (A layout)
        s8v qf[4];
        #pragma unroll
        for (int ks = 0; ks < 4; ++ks)
            qf[ks] = *reinterpret_cast<const s8v*>(
                Q + (size_t)(qrow0 + l16) * NH + ks * 32 + quad * 8);

        float m[4], ls[4];
        f4 o[8];
        #pragma unroll
        for (int r = 0; r < 4; ++r) { m[r] = -INFINITY; ls[r] = 0.f; }
        #pragma unroll
        for (int dt = 0; dt < 8; ++dt) o[dt] = (f4){0.f, 0.f, 0.f, 0.f};

        for (int kt = wave; kt < nkt; kt += 8) {
            const int kbase = kt * 64;
            const bool domask = (kt == nkt - 1);

            // S = Q K^T
            f4 s[4];
            #pragma unroll
            for (int nt = 0; nt < 4; ++nt) {
                f4 a = (f4){0.f, 0.f, 0.f, 0.f};
                #pragma unroll
                for (int ks = 0; ks < 4; ++ks) {
                    s8v kf = *reinterpret_cast<const s8v*>(
                        K + (size_t)(kbase + nt * 16 + l16) * NH + ks * 32 + quad * 8);
                    a = __builtin_amdgcn_mfma_f32_16x16x32_bf16(qf[ks], kf, a, 0, 0, 0);
                }
                s[nt] = a;
            }

            // online softmax; per-lane lsum (reduced after loop)
            #pragma unroll
            for (int r = 0; r < 4; ++r) {
                const int trow = qrow0 + quad * 4 + r;
                #pragma unroll
                for (int nt = 0; nt < 4; ++nt) {
                    float sv = s[nt][r] * scale;
                    if (domask && (kbase + nt * 16 + l16 > trow)) sv = -INFINITY;
                    s[nt][r] = sv;
                }
                float tm = fmaxf(fmaxf(s[0][r], s[1][r]), fmaxf(s[2][r], s[3][r]));
                #pragma unroll
                for (int off = 1; off < 16; off <<= 1)
                    tm = fmaxf(tm, __shfl_xor(tm, off, 64));
                const float mn = fmaxf(m[r], tm);
                const float alpha = __expf(m[r] - mn);
                m[r] = mn;
                float rs = 0.f;
                #pragma unroll
                for (int nt = 0; nt < 4; ++nt) {
                    float p = __expf(s[nt][r] - mn);
                    s[nt][r] = p;
                    rs += p;
                }
                ls[r] = ls[r] * alpha + rs;
                #pragma unroll
                for (int dt = 0; dt < 8; ++dt) o[dt][r] *= alpha;
            }

            // P (C layout) -> LDS, XOR-swizzled: pos = chunk ^ (row&7)
            #pragma unroll
            for (int nt = 0; nt < 4; ++nt)
                #pragma unroll
                for (int r = 0; r < 4; ++r) {
                    const int prow = quad * 4 + r;
                    const int swz  = ((nt * 2 + (l16 >> 3)) ^ (prow & 7)) * 8 + (l16 & 7);
                    P[wave][prow * 64 + swz] = f2bf(s[nt][r]);
                }

            // O += P @ V
            #pragma unroll
            for (int ks2 = 0; ks2 < 2; ++ks2) {
                const int pp = (ks2 * 4 + quad) ^ (l16 & 7);
                s8v pa = *reinterpret_cast<const s8v*>(&P[wave][l16 * 64 + pp * 8]);
                #pragma unroll
                for (int dt = 0; dt < 8; ++dt) {
                    s8v vf = *reinterpret_cast<const s8v*>(
                        Vt + (size_t)(dt * 16 + l16) * NT + kbase + ks2 * 32 + quad * 8);
                    o[dt] = __builtin_amdgcn_mfma_f32_16x16x32_bf16(pa, vf, o[dt], 0, 0, 0);
                }
            }
        }

        // reduce per-lane lsum across the 16-lane row group
        #pragma unroll
        for (int r = 0; r < 4; ++r) {
            float v = ls[r];
            #pragma unroll
            for (int off = 1; off < 16; off <<= 1) v += __shfl_xor(v, off, 64);
            ls[r] = v;
        }

        // ---- merge the 8 per-wave partials ----
        __syncthreads();   // previous phase's LDS reads fully done
        if (l16 == 0) {
            #pragma unroll
            for (int r = 0; r < 4; ++r) {
                Ms[wave][quad * 4 + r] = m[r];
                Ls[wave][quad * 4 + r] = ls[r];
            }
        }
        __syncthreads();

        #pragma unroll
        for (int r = 0; r < 4; ++r) {
            const int row = quad * 4 + r;
            float M = -INFINITY, lt = 0.f;
            #pragma unroll
            for (int w = 0; w < 8; ++w) M = fmaxf(M, Ms[w][row]);
            #pragma unroll
            for (int w = 0; w < 8; ++w) lt += Ls[w][row] * __expf(Ms[w][row] - M);
            float sc = __expf(m[r] - M);
            if (wave == 0 && l16 == 0) Lt[row] = lt;
            #pragma unroll
            for (int dt = 0; dt < 8; ++dt) o[dt][r] *= sc;
        }

        const int rrow = tid >> 5;          // 0..15
        const int cf   = (tid & 31) * 2;    // 0..62
        #pragma unroll
        for (int h = 0; h < 2; ++h) {
            __syncthreads();
            #pragma unroll
            for (int dtl = 0; dtl < 4; ++dtl)
                #pragma unroll
                for (int r = 0; r < 4; ++r)
                    Os[wave][quad * 4 + r][dtl * 16 + l16] = o[h * 4 + dtl][r];
            __syncthreads();
            float s0 = 0.f, s1 = 0.f;
            #pragma unroll
            for (int w = 0; w < 8; ++w) {
                s0 += Os[w][rrow][cf];
                s1 += Os[w][rrow][cf + 1];
            }
            const float rl = 1.0f / Lt[rrow];
            float2 res; res.x = s0 * rl; res.y = s1 * rl;
            *reinterpret_cast<float2*>(
                &out[((size_t)b * NT + qrow0 + rrow) * NH + h * 64 + cf]) = res;
        }
        __syncthreads();   // protect Ms/Ls/Os/Lt before next phase overwrites
    }
}

// ---------------------------------------------------------------------------
extern "C" void kernel_launch(void* const* d_in, const int* in_sizes, int n_in,
                              void* d_out, int out_size, void* d_ws, size_t ws_size,
                              hipStream_t stream) {
    const float* x  = (const float*)d_in[0];
    const float* Wk = (const float*)d_in[1];
    const float* Wq = (const float*)d_in[2];
    const float* Wv = (const float*)d_in[3];
    unsigned short* ws   = (unsigned short*)d_ws;
    unsigned short* wt   = ws;                      // 3 * 262144 (Wt: Q,K,V) bf16
    unsigned short* qws  = ws  + 786432;            // 8*2048*128  RoPE'd Q (bf16)
    unsigned short* kws  = qws + 2097152;           // 8*2048*128  RoPE'd K (bf16)
    unsigned short* vtws = kws + 2097152;           // 8*128*2048  V transposed (bf16)
    float* outp = (float*)d_out;

    wtrans_k<<<dim3(32, 3), 256, 0, stream>>>(Wk, Wq, Wv, wt);
    proj_rope<<<dim3(256, 3), 256, 0, stream>>>(x, wt, qws, kws, vtws);
    attn_k<<<dim3(64, 8), 512, 0, stream>>>(qws, kws, vtws, outp);
}